// Round 1
// baseline (459.007 us; speedup 1.0000x reference)
//
#include <hip/hip_runtime.h>
#include <hip/hip_bf16.h>
#include <cstdint>
#include <cstddef>

#define NN 8192
#define FIN 256
#define FOUT 64
#define ALPHA_SLOPE 0.2f

#define JT 128      // j columns per LDS tile
#define LDW 136     // padded LDS row pitch in bf16 elems (272 B, +16B pad kills 16-way bank conflicts)
#define JSPLIT 8    // j-range splits across blocks
#define IT 64       // i rows per block (4 waves x 16)
#define CP 68       // slab column pitch (64 feats + 1 denom + pad)

typedef short s16x8 __attribute__((ext_vector_type(8)));
typedef float f32x4 __attribute__((ext_vector_type(4)));

__device__ __forceinline__ unsigned short f2bf(float x) {
    union { float f; uint32_t u; } v; v.f = x;
    uint32_t u = v.u;
    return (unsigned short)((u + 0x7FFFu + ((u >> 16) & 1u)) >> 16);  // RNE
}

// ---------------- Kernel 1: h = input@W, s1 = h@a1, s2 = h@a2, htg = bf16(h)^T ----
__global__ __launch_bounds__(256) void k_h(
    const float* __restrict__ input, const float* __restrict__ W,
    const float* __restrict__ a,
    unsigned short* __restrict__ htg, float* __restrict__ s1, float* __restrict__ s2)
{
    const int wid  = threadIdx.x >> 6;
    const int lane = threadIdx.x & 63;     // = output feature k
    const int i    = blockIdx.x * 4 + wid; // one wave per row
    const float* inrow = input + (size_t)i * FIN;

    float acc = 0.f;
    #pragma unroll 8
    for (int c = 0; c < FIN; c += 4) {
        float4 x = *(const float4*)(inrow + c);
        acc = fmaf(x.x, W[(c + 0) * FOUT + lane], acc);
        acc = fmaf(x.y, W[(c + 1) * FOUT + lane], acc);
        acc = fmaf(x.z, W[(c + 2) * FOUT + lane], acc);
        acc = fmaf(x.w, W[(c + 3) * FOUT + lane], acc);
    }
    // transposed bf16 copy for kernel 2's B-operand staging
    htg[(size_t)lane * NN + i] = f2bf(acc);

    // s1/s2 via wave reduction
    float v1 = acc * a[lane];
    float v2 = acc * a[FOUT + lane];
    #pragma unroll
    for (int off = 32; off; off >>= 1) {
        v1 += __shfl_xor(v1, off);
        v2 += __shfl_xor(v2, off);
    }
    if (lane == 0) { s1[i] = v1; s2[i] = v2; }
}

// ---------------- Kernel 2: fused mask/exp + (P @ [h | 1]) partial sums ------------
__global__ __launch_bounds__(256) void k_attn(
    const int* __restrict__ adj,
    const unsigned short* __restrict__ htg,
    const float* __restrict__ s1g, const float* __restrict__ s2g,
    float* __restrict__ slabs)
{
    __shared__ __align__(16) unsigned short Wt[IT * LDW];  // w tile, row-major [i][j]
    __shared__ __align__(16) unsigned short Ht[80 * LDW];  // h^T tile [n][j]; rows 64..79 = denom block

    const int t  = threadIdx.x;
    const int bi = blockIdx.x >> 3;          // i-tile index (0..127)
    const int js = blockIdx.x & 7;           // j-split     (0..7)
    const int i0 = bi * IT;
    const int jbase = js * (NN / JSPLIT);

    // init denominator B-block rows once: row 64 = 1.0, rows 65..79 = 0
    {
        int n = 64 + (t >> 4);
        int c = (t & 15) * 8;
        unsigned short val = (n == 64) ? (unsigned short)0x3F80 : (unsigned short)0;
        unsigned int p = (unsigned int)val | ((unsigned int)val << 16);
        uint4 q; q.x = q.y = q.z = q.w = p;
        *(uint4*)&Ht[n * LDW + c] = q;
    }

    const int wid  = t >> 6;
    const int lane = t & 63;
    const int m    = lane & 15;
    const int quad = lane >> 4;

    f32x4 acc0 = {0,0,0,0}, acc1 = {0,0,0,0}, acc2 = {0,0,0,0},
          acc3 = {0,0,0,0}, acc4 = {0,0,0,0};

    const int wr0 = t >> 6;           // staging: base row
    const int wc  = (t & 63) * 2;     // staging: col pair

    for (int tile = 0; tile < (NN / JSPLIT) / JT; ++tile) {
        const int j0 = jbase + tile * JT;
        __syncthreads();

        // stage Ht rows 0..63 (16 KB, coalesced uint4)
        {
            int c = (t & 15) * 8;
            #pragma unroll
            for (int p = 0; p < 4; ++p) {
                int n = (t >> 4) + p * 16;
                uint4 q = *(const uint4*)(htg + (size_t)n * NN + j0 + c);
                *(uint4*)&Ht[n * LDW + c] = q;
            }
        }
        // stage Wt: w = exp(masked_leakyrelu(s1_i + s2_j))  (no shift needed: bounded)
        {
            float2 s2p = *(const float2*)(s2g + j0 + wc);
            #pragma unroll
            for (int rr = 0; rr < 16; ++rr) {
                int r = wr0 + rr * 4;
                float s1v = s1g[i0 + r];
                int2 av = *(const int2*)(adj + (size_t)(i0 + r) * NN + j0 + wc);
                float x0 = s1v + s2p.x;
                float x1 = s1v + s2p.y;
                float e0 = (av.x > 0) ? fmaxf(x0, ALPHA_SLOPE * x0) : -10.0f;
                float e1 = (av.y > 0) ? fmaxf(x1, ALPHA_SLOPE * x1) : -10.0f;
                unsigned int pk = (unsigned int)f2bf(__expf(e0))
                                | ((unsigned int)f2bf(__expf(e1)) << 16);
                *(unsigned int*)&Wt[r * LDW + wc] = pk;
            }
        }
        __syncthreads();

        // MFMA: each wave owns 16 rows (m-offset wid*16), full 80-col B
        const unsigned short* wbase = Wt + (wid * 16 + m) * LDW + quad * 8;
        const unsigned short* hbase = Ht + m * LDW + quad * 8;
        #pragma unroll
        for (int ko = 0; ko < JT; ko += 32) {
            s16x8 af = *(const s16x8*)(wbase + ko);
            s16x8 b0 = *(const s16x8*)(hbase + ko);
            s16x8 b1 = *(const s16x8*)(hbase + 16 * LDW + ko);
            s16x8 b2 = *(const s16x8*)(hbase + 32 * LDW + ko);
            s16x8 b3 = *(const s16x8*)(hbase + 48 * LDW + ko);
            s16x8 b4 = *(const s16x8*)(hbase + 64 * LDW + ko);
            acc0 = __builtin_amdgcn_mfma_f32_16x16x32_bf16(af, b0, acc0, 0, 0, 0);
            acc1 = __builtin_amdgcn_mfma_f32_16x16x32_bf16(af, b1, acc1, 0, 0, 0);
            acc2 = __builtin_amdgcn_mfma_f32_16x16x32_bf16(af, b2, acc2, 0, 0, 0);
            acc3 = __builtin_amdgcn_mfma_f32_16x16x32_bf16(af, b3, acc3, 0, 0, 0);
            acc4 = __builtin_amdgcn_mfma_f32_16x16x32_bf16(af, b4, acc4, 0, 0, 0);
        }
    }

    // epilogue: C row = quad*4 + reg, col = m
    float* slab = slabs + (size_t)js * ((size_t)NN * CP);
    const int irow0 = i0 + wid * 16 + quad * 4;
    #pragma unroll
    for (int reg = 0; reg < 4; ++reg) {
        size_t irow = (size_t)(irow0 + reg) * CP;
        slab[irow +  0 + m] = acc0[reg];
        slab[irow + 16 + m] = acc1[reg];
        slab[irow + 32 + m] = acc2[reg];
        slab[irow + 48 + m] = acc3[reg];
        if (m == 0) slab[irow + 64] = acc4[reg];
    }
}

// ---------------- Kernel 3: reduce splits, normalize, ELU --------------------------
__global__ __launch_bounds__(256) void k_norm(
    const float* __restrict__ slabs, float* __restrict__ out)
{
    int gid = blockIdx.x * 256 + threadIdx.x;
    int i = gid >> 6, k = gid & 63;
    float num = 0.f, den = 0.f;
    #pragma unroll
    for (int js = 0; js < JSPLIT; ++js) {
        const float* row = slabs + (size_t)js * ((size_t)NN * CP) + (size_t)i * CP;
        num += row[k];
        den += row[64];
    }
    float v = num / den;
    out[gid] = (v > 0.f) ? v : (__expf(v) - 1.f);
}

// ---------------- launch -----------------------------------------------------------
extern "C" void kernel_launch(void* const* d_in, const int* in_sizes, int n_in,
                              void* d_out, int out_size, void* d_ws, size_t ws_size,
                              hipStream_t stream) {
    const float* input = (const float*)d_in[0];
    const int*   adj   = (const int*)d_in[1];
    const float* W     = (const float*)d_in[2];
    const float* a     = (const float*)d_in[3];
    float* out = (float*)d_out;

    char* ws = (char*)d_ws;
    float* slabs = (float*)ws;
    size_t off = (size_t)JSPLIT * NN * CP * sizeof(float);      // 17.8 MB
    unsigned short* htg = (unsigned short*)(ws + off);
    off += (size_t)FOUT * NN * sizeof(unsigned short);          // 1 MB
    float* s1 = (float*)(ws + off); off += NN * sizeof(float);
    float* s2 = (float*)(ws + off);

    k_h   <<<NN / 4, 256, 0, stream>>>(input, W, a, htg, s1, s2);
    k_attn<<<(NN / IT) * JSPLIT, 256, 0, stream>>>(adj, htg, s1, s2, slabs);
    k_norm<<<NN * FOUT / 256, 256, 0, stream>>>(slabs, out);
}

// Round 2
// 455.055 us; speedup vs baseline: 1.0087x; 1.0087x over previous
//
#include <hip/hip_runtime.h>
#include <hip/hip_bf16.h>
#include <cstdint>
#include <cstddef>

#define NN 8192
#define FIN 256
#define FOUT 64
#define ALPHA_SLOPE 0.2f
#define EXP_M10 4.5399929762484854e-05f   // exp(-10)

#define JSPLIT 8    // j-range splits (each wave covers 1024 j's)
#define CP 68       // slab column pitch (64 feats + 1 denom + pad)

typedef short s16x8 __attribute__((ext_vector_type(8)));
typedef float f32x4 __attribute__((ext_vector_type(4)));

__device__ __forceinline__ unsigned short f2bf(float x) {
    union { float f; uint32_t u; } v; v.f = x;
    uint32_t u = v.u;
    return (unsigned short)((u + 0x7FFFu + ((u >> 16) & 1u)) >> 16);  // RNE
}

// ---------------- Kernel 1: h = input@W, s1 = h@a1, s2 = h@a2, htg = bf16(h)^T ----
// 512 blocks x 16 rows. Wave w computes 4 rows (lane = feature). LDS transpose
// so the htg (h^T) global write is 8B-chunk coalesced instead of 2B scatter.
__global__ __launch_bounds__(256) void k_h(
    const float* __restrict__ input, const float* __restrict__ W,
    const float* __restrict__ a,
    unsigned short* __restrict__ htg, float* __restrict__ s1, float* __restrict__ s2)
{
    __shared__ __align__(16) unsigned short tile[64][28];  // [feat][row], pitch 28 shorts
    const int wid  = threadIdx.x >> 6;
    const int lane = threadIdx.x & 63;
    const int i0   = blockIdx.x * 16;
    const int r0   = wid * 4;                 // wave's 4 rows within block
    const float* inb = input + (size_t)(i0 + r0) * FIN;

    float acc0 = 0.f, acc1 = 0.f, acc2 = 0.f, acc3 = 0.f;
    #pragma unroll 4
    for (int c = 0; c < FIN; c += 4) {
        float w0 = W[(c + 0) * FOUT + lane];
        float w1 = W[(c + 1) * FOUT + lane];
        float w2 = W[(c + 2) * FOUT + lane];
        float w3 = W[(c + 3) * FOUT + lane];
        float4 x0 = *(const float4*)(inb + 0 * FIN + c);
        float4 x1 = *(const float4*)(inb + 1 * FIN + c);
        float4 x2 = *(const float4*)(inb + 2 * FIN + c);
        float4 x3 = *(const float4*)(inb + 3 * FIN + c);
        acc0 = fmaf(x0.x, w0, fmaf(x0.y, w1, fmaf(x0.z, w2, fmaf(x0.w, w3, acc0))));
        acc1 = fmaf(x1.x, w0, fmaf(x1.y, w1, fmaf(x1.z, w2, fmaf(x1.w, w3, acc1))));
        acc2 = fmaf(x2.x, w0, fmaf(x2.y, w1, fmaf(x2.z, w2, fmaf(x2.w, w3, acc2))));
        acc3 = fmaf(x3.x, w0, fmaf(x3.y, w1, fmaf(x3.z, w2, fmaf(x3.w, w3, acc3))));
    }

    const float a1v = a[lane], a2v = a[FOUT + lane];
    float accs[4] = {acc0, acc1, acc2, acc3};
    #pragma unroll
    for (int r = 0; r < 4; ++r) {
        float v1 = accs[r] * a1v;
        float v2 = accs[r] * a2v;
        #pragma unroll
        for (int off = 32; off; off >>= 1) {
            v1 += __shfl_xor(v1, off);
            v2 += __shfl_xor(v2, off);
        }
        if (lane == 0) { s1[i0 + r0 + r] = v1; s2[i0 + r0 + r] = v2; }
        tile[lane][r0 + r] = f2bf(accs[r]);
    }
    __syncthreads();

    // write htg[feat][i0..i0+15]: thread t -> feat = t>>2, 4-short chunk (t&3)
    const int feat = threadIdx.x >> 2;
    const int cg   = (threadIdx.x & 3) * 4;
    uint2 q = *(const uint2*)&tile[feat][cg];
    *(uint2*)(htg + (size_t)feat * NN + i0 + cg) = q;
}

// ---------------- Kernel 2: fused mask/exp + (P @ [h | 1]) — no LDS, no barriers ---
// Each wave owns a 16-row i-tile and a 1024-wide j-range. A-fragment (the exp
// weights) is computed in-register straight from adj; B-fragments load directly
// from L2-resident htg; denominator column is a constant fragment.
__global__ __launch_bounds__(256) void k_attn(
    const int* __restrict__ adj,
    const unsigned short* __restrict__ htg,
    const float* __restrict__ s1g, const float* __restrict__ s2g,
    float* __restrict__ slabs)
{
    const int t    = threadIdx.x;
    const int wid  = t >> 6;
    const int lane = t & 63;
    const int gw   = blockIdx.x * 4 + wid;   // global wave id, 0..4095
    const int mi   = gw >> 3;                // i-tile index (0..511)
    const int js   = gw & 7;                 // j-split (0..7)
    const int m    = lane & 15;
    const int quad = lane >> 4;
    const int irow = mi * 16 + m;            // this lane's A-row
    const int jb   = js * (NN / JSPLIT) + quad * 8;

    const float s1v = s1g[irow];

    const short bd = (m == 0) ? (short)0x3F80 : (short)0;  // bf16 1.0 or 0
    const s16x8 bden = {bd, bd, bd, bd, bd, bd, bd, bd};

    f32x4 acc0 = {0,0,0,0}, acc1 = {0,0,0,0}, acc2 = {0,0,0,0},
          acc3 = {0,0,0,0}, acc4 = {0,0,0,0};

    const int*   aptr = adj + (size_t)irow * NN + jb;
    const float* s2p  = s2g + jb;
    const unsigned short* h0 = htg + (size_t)(m +  0) * NN + jb;
    const unsigned short* h1 = htg + (size_t)(m + 16) * NN + jb;
    const unsigned short* h2 = htg + (size_t)(m + 32) * NN + jb;
    const unsigned short* h3 = htg + (size_t)(m + 48) * NN + jb;

    #pragma unroll 2
    for (int ko = 0; ko < (NN / JSPLIT) / 32; ++ko) {
        int4   av0 = *(const int4*)(aptr);
        int4   av1 = *(const int4*)(aptr + 4);
        float4 sa  = *(const float4*)(s2p);
        float4 sb  = *(const float4*)(s2p + 4);
        s16x8  b0  = *(const s16x8*)(h0);
        s16x8  b1  = *(const s16x8*)(h1);
        s16x8  b2  = *(const s16x8*)(h2);
        s16x8  b3  = *(const s16x8*)(h3);

        float x0 = s1v + sa.x, x1 = s1v + sa.y, x2 = s1v + sa.z, x3 = s1v + sa.w;
        float x4 = s1v + sb.x, x5 = s1v + sb.y, x6 = s1v + sb.z, x7 = s1v + sb.w;
        float w0 = (av0.x > 0) ? __expf(fmaxf(x0, ALPHA_SLOPE * x0)) : EXP_M10;
        float w1 = (av0.y > 0) ? __expf(fmaxf(x1, ALPHA_SLOPE * x1)) : EXP_M10;
        float w2 = (av0.z > 0) ? __expf(fmaxf(x2, ALPHA_SLOPE * x2)) : EXP_M10;
        float w3 = (av0.w > 0) ? __expf(fmaxf(x3, ALPHA_SLOPE * x3)) : EXP_M10;
        float w4 = (av1.x > 0) ? __expf(fmaxf(x4, ALPHA_SLOPE * x4)) : EXP_M10;
        float w5 = (av1.y > 0) ? __expf(fmaxf(x5, ALPHA_SLOPE * x5)) : EXP_M10;
        float w6 = (av1.z > 0) ? __expf(fmaxf(x6, ALPHA_SLOPE * x6)) : EXP_M10;
        float w7 = (av1.w > 0) ? __expf(fmaxf(x7, ALPHA_SLOPE * x7)) : EXP_M10;

        s16x8 af;
        af[0] = (short)f2bf(w0); af[1] = (short)f2bf(w1);
        af[2] = (short)f2bf(w2); af[3] = (short)f2bf(w3);
        af[4] = (short)f2bf(w4); af[5] = (short)f2bf(w5);
        af[6] = (short)f2bf(w6); af[7] = (short)f2bf(w7);

        acc0 = __builtin_amdgcn_mfma_f32_16x16x32_bf16(af, b0,   acc0, 0, 0, 0);
        acc1 = __builtin_amdgcn_mfma_f32_16x16x32_bf16(af, b1,   acc1, 0, 0, 0);
        acc2 = __builtin_amdgcn_mfma_f32_16x16x32_bf16(af, b2,   acc2, 0, 0, 0);
        acc3 = __builtin_amdgcn_mfma_f32_16x16x32_bf16(af, b3,   acc3, 0, 0, 0);
        acc4 = __builtin_amdgcn_mfma_f32_16x16x32_bf16(af, bden, acc4, 0, 0, 0);

        aptr += 32; s2p += 32; h0 += 32; h1 += 32; h2 += 32; h3 += 32;
    }

    // epilogue: C row = quad*4 + reg (i), col = m (feature within 16-block)
    float* slab = slabs + (size_t)js * ((size_t)NN * CP);
    const int r0 = mi * 16 + quad * 4;
    #pragma unroll
    for (int reg = 0; reg < 4; ++reg) {
        size_t ro = (size_t)(r0 + reg) * CP;
        slab[ro +  0 + m] = acc0[reg];
        slab[ro + 16 + m] = acc1[reg];
        slab[ro + 32 + m] = acc2[reg];
        slab[ro + 48 + m] = acc3[reg];
        if (m == 0) slab[ro + 64] = acc4[reg];
    }
}

// ---------------- Kernel 3: reduce splits, normalize, ELU --------------------------
__global__ __launch_bounds__(256) void k_norm(
    const float* __restrict__ slabs, float* __restrict__ out)
{
    int gid = blockIdx.x * 256 + threadIdx.x;
    int i = gid >> 6, k = gid & 63;
    float num = 0.f, den = 0.f;
    #pragma unroll
    for (int js = 0; js < JSPLIT; ++js) {
        const float* row = slabs + (size_t)js * ((size_t)NN * CP) + (size_t)i * CP;
        num += row[k];
        den += row[64];
    }
    float v = num / den;
    out[gid] = (v > 0.f) ? v : (__expf(v) - 1.f);
}

// ---------------- launch -----------------------------------------------------------
extern "C" void kernel_launch(void* const* d_in, const int* in_sizes, int n_in,
                              void* d_out, int out_size, void* d_ws, size_t ws_size,
                              hipStream_t stream) {
    const float* input = (const float*)d_in[0];
    const int*   adj   = (const int*)d_in[1];
    const float* W     = (const float*)d_in[2];
    const float* a     = (const float*)d_in[3];
    float* out = (float*)d_out;

    char* ws = (char*)d_ws;
    float* slabs = (float*)ws;
    size_t off = (size_t)JSPLIT * NN * CP * sizeof(float);      // 17.8 MB
    unsigned short* htg = (unsigned short*)(ws + off);
    off += (size_t)FOUT * NN * sizeof(unsigned short);          // 1 MB
    float* s1 = (float*)(ws + off); off += NN * sizeof(float);
    float* s2 = (float*)(ws + off);

    k_h   <<<NN / 16, 256, 0, stream>>>(input, W, a, htg, s1, s2);
    k_attn<<<(NN / 16) * JSPLIT / 4, 256, 0, stream>>>(adj, htg, s1, s2, slabs);
    k_norm<<<NN * FOUT / 256, 256, 0, stream>>>(slabs, out);
}